// Round 4
// baseline (88.177 us; speedup 1.0000x reference)
//
#include <hip/hip_runtime.h>

// GraphProjection, round 7: wave = point. Zero LDS, zero barriers.
//
// Post-mortem history: r3 (80us, LDS-staged) -> r6 swizzle removed bank
// conflicts but REGRESSED (86us): conflicts were absorbed by TLP; the family
// is issue/latency-bound.  r5 (151us) showed per-dword redundant index math
// is fatal; r4 (90us) showed NT partial-line stores are fatal.
//
// This version flips the work mapping so ALL per-point state is wave-uniform:
//   * one wave owns one point; 4 waves/block, grid = ceil(N/4) blocks.
//   * coords via scalar loads (p is readfirstlane-uniform); projection +
//     weights computed once per point (redundant across lanes, ~100 VALU).
//   * corner offsets readfirstlane'd into SGPR base pairs: per-chunk loads
//     are global_load_dword(voffset=lane*4, SGPR base, imm offset) -- zero
//     per-load VALU addressing.
//   * channel = lane + 64k, level is a TEMPLATE param (all C % 64 == 0):
//     loads lane-consecutive 256B coalesced; stores lane-consecutive scalar
//     dwords = fully coalesced at any byte offset (the +3 never matters).
//   * 15 independent chunks/point -> deep load pipelining; no LDS/low VGPR
//     -> 32 waves/CU.
//   * REGULAR stores (no nontemporal): L2 merges row-edge partial lines;
//     fill kernel proves regular stores reach 6.8-7.0 TB/s.

#define ROWF 963   // 3 coords + 960 samples

template<int H, int C, int CHBASE>
__device__ __forceinline__ void do_level(
    const float* __restrict__ f, float h, float w,
    float* __restrict__ orow, int lane)
{
    const float scale = (float)H / 224.0f;   // exact power-of-2 ratio
    const float x = h * scale, y = w * scale;
    const float x1f = floorf(x), x2f = fminf(ceilf(x), (float)(H - 1));
    const float y1f = floorf(y), y2f = fminf(ceilf(y), (float)(H - 1));
    const int xi1 = (int)x1f, xi2 = (int)x2f;
    const int yi1 = (int)y1f, yi2 = (int)y2f;

    const float w11 = (x2f - x) * (y2f - y);
    const float w21 = (x - x1f) * (y2f - y);
    const float w12 = (x2f - x) * (y - y1f);
    const float w22 = (x - x1f) * (y - y1f);

    // wave-uniform corner offsets -> SGPR; loads become SGPR-base + lane voffset
    const float* q11 = f + __builtin_amdgcn_readfirstlane((xi1 * H + yi1) * C);
    const float* q21 = f + __builtin_amdgcn_readfirstlane((xi2 * H + yi1) * C);
    const float* q12 = f + __builtin_amdgcn_readfirstlane((xi1 * H + yi2) * C);
    const float* q22 = f + __builtin_amdgcn_readfirstlane((xi2 * H + yi2) * C);

    #pragma unroll
    for (int k = 0; k < C / 64; ++k) {
        const int c = lane + 64 * k;
        orow[CHBASE + c] = w11 * q11[c] + w21 * q21[c]
                         + w12 * q12[c] + w22 * q22[c];
    }
}

__global__ __launch_bounds__(256) void graphproj_kernel(
    const float* __restrict__ coords,
    const float* __restrict__ f1, const float* __restrict__ f2,
    const float* __restrict__ f3, const float* __restrict__ f4,
    float* __restrict__ out, int N)
{
    const int lane = threadIdx.x & 63;
    const int wv   = __builtin_amdgcn_readfirstlane(threadIdx.x >> 6);
    const int p    = blockIdx.x * 4 + wv;
    if (p >= N) return;

    // wave-uniform coord fetch (scalar loads)
    const float X = coords[p * 3 + 0];
    const float Y = coords[p * 3 + 1];
    const float Z = coords[p * 3 + 2];

    float h = 250.0f * (-Y) / (-Z) + 112.0f;
    float w = 250.0f * X / (-Z) + 112.0f;
    h = fminf(fmaxf(h, 0.0f), 223.0f);
    w = fminf(fmaxf(w, 0.0f), 223.0f);

    float* orow = out + (size_t)p * ROWF + 3;

    // coords prefix (3 dwords; L2 merges with neighbor row's tail line)
    if (lane < 3) {
        out[(size_t)p * ROWF + lane] = (lane == 0) ? X : (lane == 1) ? Y : Z;
    }

    do_level<56,  64,   0>(f1, h, w, orow, lane);
    do_level<28, 128,  64>(f2, h, w, orow, lane);
    do_level<14, 256, 192>(f3, h, w, orow, lane);
    do_level< 7, 512, 448>(f4, h, w, orow, lane);
}

extern "C" void kernel_launch(void* const* d_in, const int* in_sizes, int n_in,
                              void* d_out, int out_size, void* d_ws, size_t ws_size,
                              hipStream_t stream) {
    const float* coords = (const float*)d_in[0];
    const float* f1 = (const float*)d_in[1];
    const float* f2 = (const float*)d_in[2];
    const float* f3 = (const float*)d_in[3];
    const float* f4 = (const float*)d_in[4];
    float* out = (float*)d_out;
    const int N = in_sizes[0] / 3;

    const int blocks = (N + 3) / 4;
    graphproj_kernel<<<blocks, 256, 0, stream>>>(coords, f1, f2, f3, f4, out, N);
}